// Round 5
// baseline (453.449 us; speedup 1.0000x reference)
//
#include <hip/hip_runtime.h>
#include <hip/hip_bf16.h>
#include <cstdint>
#include <cstddef>

#define B_ 2
#define N_ 8192
#define C_ 128
#define K_ 16
#define NK_ (N_ * K_)
#define EPS_ 1e-5f
#define SLOPE_ 0.2f
#define INF_ 3.0e38f

// ---------------- workspace layout (bytes) ----------------
static constexpr size_t OFF_IDX   = 0x000000;   // int[B*N*16]      1 MB
static constexpr size_t OFF_CPK   = 0x100000;   // float4[B*N]      256 KB
static constexpr size_t OFF_CPK64 = 0x140000;   // double4[B*N]     512 KB
static constexpr size_t OFF_ACC   = 0x1C0000;   // float[2048]      8 KB
static constexpr size_t OFF_WC1   = 0x1D0000;   // float[256*128]   128 KB
static constexpr size_t OFF_WC2   = 0x1F0000;   // float[512*128]   256 KB
static constexpr size_t OFF_X3T   = 0x240000;                          // float[B*N*512] 32 MB
static constexpr size_t OFF_PQ    = OFF_X3T + (size_t)B_ * N_ * 512 * 4; // 32 MB shared: pq1 -> pq2 -> ht
// total: ~66.25 MB

// f32 distance, individually rounded (prefilter only)
__device__ __forceinline__ float np_dist(float4 a, float4 b) {
  float t1 = __fmul_rn(a.x, b.x);
  float t2 = __fmul_rn(a.y, b.y);
  float t3 = __fmul_rn(a.z, b.z);
  float dot = __fadd_rn(__fadd_rn(t1, t2), t3);
  return __fsub_rn(__fadd_rn(a.w, b.w), __fmul_rn(2.0f, dot));
}

// ---------------- prep: combined weights, packed coords (f32+f64), zero accumulators ----------------
__global__ void prep_kernel(const float* __restrict__ coords,
                            const float* __restrict__ W1,
                            const float* __restrict__ W2,
                            float* __restrict__ wc1, float* __restrict__ wc2,
                            float4* __restrict__ cpk, double4* __restrict__ cpk64,
                            float* __restrict__ acc) {
  int tid = blockIdx.x * 256 + threadIdx.x;
  if (tid < 256 * 128) {
    int o = tid >> 7, i = tid & 127;
    float v;
    if (o < 128) v = W1[o * 256 + i] - W1[o * 256 + 128 + i];
    else         v = W1[(o - 128) * 256 + 128 + i];
    wc1[tid] = v;
  } else if (tid < 256 * 128 + 512 * 128) {
    int t2 = tid - 256 * 128;
    int o = t2 >> 7, i = t2 & 127;
    float v;
    if (o < 256) v = W2[o * 256 + i] - W2[o * 256 + 128 + i];
    else         v = W2[(o - 256) * 256 + 128 + i];
    wc2[t2] = v;
  } else if (tid < 256 * 128 + 512 * 128 + B_ * N_) {
    int q = tid - (256 * 128 + 512 * 128);
    int b = q >> 13, n = q & (N_ - 1);
    float x = coords[(b * 3 + 0) * N_ + n];
    float y = coords[(b * 3 + 1) * N_ + n];
    float z = coords[(b * 3 + 2) * N_ + n];
    float sq = __fadd_rn(__fadd_rn(__fmul_rn(x, x), __fmul_rn(y, y)), __fmul_rn(z, z));
    cpk[q] = make_float4(x, y, z, sq);
    double xd = (double)x, yd = (double)y, zd = (double)z;
    double sqd = (xd * xd + yd * yd) + zd * zd;
    cpk64[q] = make_double4(xd, yd, zd, sqd);
  } else if (tid < 256 * 128 + 512 * 128 + B_ * N_ + 2048) {
    acc[tid - (256 * 128 + 512 * 128 + B_ * N_)] = 0.f;
  }
}

// ---------------- transpose x0 (B,128,N) -> x3t[b][n][0:128] (ld 512) ----------------
__global__ __launch_bounds__(256) void transpose_kernel(const float* __restrict__ x0,
                                                        float* __restrict__ x3t) {
  __shared__ float tile[64 * 68];
  int b = blockIdx.z, c0 = blockIdx.y * 64, n0 = blockIdx.x * 64;
  int t = threadIdx.x;
  int r = t >> 4;          // 0..15
  int c4 = (t & 15) * 4;   // 0..60
#pragma unroll
  for (int i = 0; i < 4; ++i) {
    int row = r + i * 16;  // c-local
    float4 v = *(const float4*)&x0[((size_t)(b * C_ + c0 + row)) * N_ + n0 + c4];
    *(float4*)&tile[row * 68 + c4] = v;   // tile[c_local][n_local]
  }
  __syncthreads();
#pragma unroll
  for (int i = 0; i < 4; ++i) {
    int nl = r + i * 16;   // n-local
    float4 v = make_float4(tile[(c4 + 0) * 68 + nl], tile[(c4 + 1) * 68 + nl],
                           tile[(c4 + 2) * 68 + nl], tile[(c4 + 3) * 68 + nl]);
    *(float4*)&x3t[((size_t)(b * N_ + n0 + nl)) * 512 + c0 + c4] = v;
  }
}

// ascending bitonic sort of 64 float (d, ix) pairs across a wave, key (d, then ix)
__device__ __forceinline__ void bsort64(float& d, int& ix, int lane) {
#pragma unroll
  for (int k2 = 2; k2 <= 64; k2 <<= 1) {
#pragma unroll
    for (int j = k2 >> 1; j > 0; j >>= 1) {
      float od = __shfl_xor(d, j, 64);
      int oi = __shfl_xor(ix, j, 64);
      bool up = ((lane & k2) == 0);
      bool lower = ((lane & j) == 0);
      bool takeMin = (lower == up);
      bool less = (od < d) || (od == d && oi < ix);
      if (takeMin == less) { d = od; ix = oi; }
    }
  }
}

// ascending bitonic sort of 64 double (d, ix) pairs across a wave, key (d, then ix)
__device__ __forceinline__ void bsort64d(double& d, int& ix, int lane) {
#pragma unroll
  for (int k2 = 2; k2 <= 64; k2 <<= 1) {
#pragma unroll
    for (int j = k2 >> 1; j > 0; j >>= 1) {
      double od = __shfl_xor(d, j, 64);
      int oi = __shfl_xor(ix, j, 64);
      bool up = ((lane & k2) == 0);
      bool lower = ((lane & j) == 0);
      bool takeMin = (lower == up);
      bool less = (od < d) || (od == d && oi < ix);
      if (takeMin == less) { d = od; ix = oi; }
    }
  }
}

// ---------------- KNN: f32 prefilter, exact-f64 select; one wave per query ----------------
__global__ __launch_bounds__(256) void knn_kernel(const float4* __restrict__ cpk,
                                                  const double4* __restrict__ cpk64,
                                                  int* __restrict__ idxout) {
  __shared__ double sdd[4][128];
  __shared__ int    sii[4][128];
  int lane = threadIdx.x & 63;
  int wv = threadIdx.x >> 6;
  int q = blockIdx.x * 4 + wv;           // 0..B*N-1
  int b = q >> 13;
  int n = q & (N_ - 1);
  float4 me = cpk[q];
  const float4* cb = cpk + (size_t)b * N_;
  const double4* cb64 = cpk64 + (size_t)b * N_;

  // Phase A: per-lane f32 min over its 128 candidates
  float dmin = INF_;
  for (int i = 0; i < 128; ++i) {
    int m = i * 64 + lane;
    float dist = np_dist(me, cb[m]);
    if (m == n) dist = INF_;
    dmin = fminf(dmin, dist);
  }
  // T = 16th smallest lane-min: >=16 distinct candidates have d32 <= T => D16_32 <= T
  float v = dmin;
  int dummy = lane;
  bsort64(v, dummy, lane);
  float T = __shfl(v, 15, 64);
  float Tf_wide = T + 2e-3f;           // f32 pre-screen for the f64 path
  double Td = (double)T + 1e-3;        // covers |d32-d64| <= ~1e-4 with margin

  // Phase B: f64 distances for near candidates; compact survivors (d64 <= Td), m-order
  double4 me64 = cb64[n];
  int basecnt = 0;
  for (int i = 0; i < 128; ++i) {
    int m = i * 64 + lane;
    float dist32 = np_dist(me, cb[m]);
    bool near = (dist32 <= Tf_wide) && (m != n);
    double dist = 1e300;
    if (near) {
      double4 c = cb64[m];
      double dot = (me64.x * c.x + me64.y * c.y) + me64.z * c.z;
      dist = (me64.w + c.w) - 2.0 * dot;
    }
    bool p = near && (dist <= Td);
    unsigned long long mk = __ballot(p);
    int pos = basecnt + (int)__popcll(mk & ((1ull << lane) - 1ull));
    if (p && pos < 128) { sdd[wv][pos] = dist; sii[wv][pos] = m; }
    basecnt += (int)__popcll(mk);
  }
  __syncthreads();

  // Phase C: sort survivors by (d64, idx); take 16 smallest
  int cnt = basecnt < 128 ? basecnt : 128;
  int c1 = cnt < 64 ? cnt : 64;
  double d = (lane < c1) ? sdd[wv][lane] : 1e300;
  int ix = (lane < c1) ? sii[wv][lane] : 0x7FFFFFFF;
  bsort64d(d, ix, lane);
  if (cnt > 64) {
    double d2 = (lane + 64 < cnt) ? sdd[wv][lane + 64] : 1e300;
    int ix2 = (lane + 64 < cnt) ? sii[wv][lane + 64] : 0x7FFFFFFF;
    bsort64d(d2, ix2, lane);
    int src = (lane - 16) & 63;
    double dB = __shfl(d2, src, 64);
    int iB = __shfl(ix2, src, 64);
    double nd = (lane < 16) ? d : ((lane < 32) ? dB : 1e300);
    int nix = (lane < 16) ? ix : ((lane < 32) ? iB : 0x7FFFFFFF);
    bsort64d(nd, nix, lane);
    d = nd; ix = nix;
  }
  if (lane < 16) idxout[(size_t)q * 16 + lane] = ix;
}

// ---------------- generic f32 tiled GEMM: C[b][n][o] = sum_k X[b][n][k]*W[o][k] ----------------
__global__ __launch_bounds__(256) void gemm_kernel(const float* __restrict__ X, int ldx,
                                                   const float* __restrict__ W, int ldw,
                                                   float* __restrict__ Cc, int ldc,
                                                   int Ktot) {
  __shared__ float Xs[64 * 34];
  __shared__ float Ws[64 * 34];
  int b = blockIdx.z;
  int n0 = blockIdx.x * 64, o0 = blockIdx.y * 64;
  int t = threadIdx.x;
  int tx = t & 15, ty = t >> 4;
  const float* Xb = X + (size_t)(b * N_ + n0) * ldx;
  float acc[4][4] = {};
  int lr = t >> 2;           // 0..63
  int lc = (t & 3) * 8;      // 0,8,16,24
  for (int kt = 0; kt < Ktot; kt += 32) {
    float4 xa = *(const float4*)&Xb[(size_t)lr * ldx + kt + lc];
    float4 xb2 = *(const float4*)&Xb[(size_t)lr * ldx + kt + lc + 4];
    float4 wa = *(const float4*)&W[(size_t)(o0 + lr) * ldw + kt + lc];
    float4 wb = *(const float4*)&W[(size_t)(o0 + lr) * ldw + kt + lc + 4];
    *(float2*)&Xs[lr * 34 + lc + 0] = make_float2(xa.x, xa.y);
    *(float2*)&Xs[lr * 34 + lc + 2] = make_float2(xa.z, xa.w);
    *(float2*)&Xs[lr * 34 + lc + 4] = make_float2(xb2.x, xb2.y);
    *(float2*)&Xs[lr * 34 + lc + 6] = make_float2(xb2.z, xb2.w);
    *(float2*)&Ws[lr * 34 + lc + 0] = make_float2(wa.x, wa.y);
    *(float2*)&Ws[lr * 34 + lc + 2] = make_float2(wa.z, wa.w);
    *(float2*)&Ws[lr * 34 + lc + 4] = make_float2(wb.x, wb.y);
    *(float2*)&Ws[lr * 34 + lc + 6] = make_float2(wb.z, wb.w);
    __syncthreads();
#pragma unroll
    for (int kk = 0; kk < 32; ++kk) {
      float a0 = Xs[(ty * 4 + 0) * 34 + kk];
      float a1 = Xs[(ty * 4 + 1) * 34 + kk];
      float a2 = Xs[(ty * 4 + 2) * 34 + kk];
      float a3 = Xs[(ty * 4 + 3) * 34 + kk];
      float b0 = Ws[(tx * 4 + 0) * 34 + kk];
      float b1 = Ws[(tx * 4 + 1) * 34 + kk];
      float b2 = Ws[(tx * 4 + 2) * 34 + kk];
      float b3 = Ws[(tx * 4 + 3) * 34 + kk];
      acc[0][0] = fmaf(a0, b0, acc[0][0]); acc[0][1] = fmaf(a0, b1, acc[0][1]);
      acc[0][2] = fmaf(a0, b2, acc[0][2]); acc[0][3] = fmaf(a0, b3, acc[0][3]);
      acc[1][0] = fmaf(a1, b0, acc[1][0]); acc[1][1] = fmaf(a1, b1, acc[1][1]);
      acc[1][2] = fmaf(a1, b2, acc[1][2]); acc[1][3] = fmaf(a1, b3, acc[1][3]);
      acc[2][0] = fmaf(a2, b0, acc[2][0]); acc[2][1] = fmaf(a2, b1, acc[2][1]);
      acc[2][2] = fmaf(a2, b2, acc[2][2]); acc[2][3] = fmaf(a2, b3, acc[2][3]);
      acc[3][0] = fmaf(a3, b0, acc[3][0]); acc[3][1] = fmaf(a3, b1, acc[3][1]);
      acc[3][2] = fmaf(a3, b2, acc[3][2]); acc[3][3] = fmaf(a3, b3, acc[3][3]);
    }
    __syncthreads();
  }
#pragma unroll
  for (int i = 0; i < 4; ++i) {
    float4 v = make_float4(acc[i][0], acc[i][1], acc[i][2], acc[i][3]);
    *(float4*)&Cc[(size_t)(b * N_ + n0 + ty * 4 + i) * ldc + o0 + tx * 4] = v;
  }
}

// ---------------- edge gather + max/sum/sumsq ----------------
template <int CO>
__global__ __launch_bounds__(256) void edge_kernel(const float* __restrict__ PQ,
                                                   const int* __restrict__ idx,
                                                   float* __restrict__ Mout,  // x3t+coloff, ld 512
                                                   float* __restrict__ acc) {
  constexpr int NG = 256 / CO;
  __shared__ float r1[256], r2[256];
  int b = blockIdx.y;
  int n0 = blockIdx.x * 64;
  int t = threadIdx.x;
  int o = t & (CO - 1);
  int qg = t / CO;
  float s1 = 0.f, s2 = 0.f;
  const float* PQb = PQ + (size_t)b * N_ * (2 * CO);
  for (int qq = qg; qq < 64; qq += NG) {
    int n = n0 + qq;
    const int4* ip = (const int4*)&idx[(size_t)(b * N_ + n) * 16];
    int4 i0 = ip[0], i1 = ip[1], i2 = ip[2], i3 = ip[3];
    float p = PQb[(size_t)n * (2 * CO) + o];
    float hmax = -INF_;
#define EDGE_STEP(mm)                                                    \
    { int mc = (mm) & (N_ - 1);                                          \
      float vv = PQb[(size_t)mc * (2 * CO) + CO + o];                    \
      float h = p + vv;                                                  \
      hmax = fmaxf(hmax, h); s1 += h; s2 = fmaf(h, h, s2); }
    EDGE_STEP(i0.x) EDGE_STEP(i0.y) EDGE_STEP(i0.z) EDGE_STEP(i0.w)
    EDGE_STEP(i1.x) EDGE_STEP(i1.y) EDGE_STEP(i1.z) EDGE_STEP(i1.w)
    EDGE_STEP(i2.x) EDGE_STEP(i2.y) EDGE_STEP(i2.z) EDGE_STEP(i2.w)
    EDGE_STEP(i3.x) EDGE_STEP(i3.y) EDGE_STEP(i3.z) EDGE_STEP(i3.w)
#undef EDGE_STEP
    Mout[(size_t)(b * N_ + n) * 512 + o] = hmax;
  }
  r1[t] = s1; r2[t] = s2;
  __syncthreads();
  if (t < CO) {
#pragma unroll
    for (int g = 1; g < NG; ++g) { s1 += r1[t + g * CO]; s2 += r2[t + g * CO]; }
    atomicAdd(&acc[(b * CO + o) * 2 + 0], s1);
    atomicAdd(&acc[(b * CO + o) * 2 + 1], s2);
  }
}

// ---------------- in-place instance-norm + leaky (after max-over-k) ----------------
template <int CO>
__global__ void norm_kernel(float* __restrict__ M, const float* __restrict__ acc) {
  int tid = blockIdx.x * 256 + threadIdx.x;  // over B*N*CO
  int o = tid & (CO - 1);
  int bn = tid / CO;
  int b = bn >> 13;
  float s1 = acc[(b * CO + o) * 2], s2 = acc[(b * CO + o) * 2 + 1];
  const float inv = 1.f / (float)NK_;
  float mean = s1 * inv;
  float var = fmaf(s2, inv, -mean * mean);
  float rs = rsqrtf(var + EPS_);
  float v = M[(size_t)bn * 512 + o];
  float y = (v - mean) * rs;
  M[(size_t)bn * 512 + o] = y > 0.f ? y : SLOPE_ * y;
}

// ---------------- column sums for final inorm ----------------
__global__ __launch_bounds__(256) void colred_kernel(const float* __restrict__ H,
                                                     float* __restrict__ acc3) {
  __shared__ float r1[256], r2[256];
  int b = blockIdx.y;
  int n0 = blockIdx.x * 256;
  int t = threadIdx.x;
  int o = t & 127, half = t >> 7;
  float s1 = 0.f, s2 = 0.f;
  for (int i = 0; i < 128; ++i) {
    int n = n0 + half * 128 + i;
    float v = H[(size_t)(b * N_ + n) * 128 + o];
    s1 += v; s2 = fmaf(v, v, s2);
  }
  r1[t] = s1; r2[t] = s2;
  __syncthreads();
  if (t < 128) {
    s1 = r1[t] + r1[t + 128];
    s2 = r2[t] + r2[t + 128];
    atomicAdd(&acc3[(b * 128 + o) * 2 + 0], s1);
    atomicAdd(&acc3[(b * 128 + o) * 2 + 1], s2);
  }
}

// ---------------- final: norm + leaky + transpose to (B,128,N) f32 ----------------
__global__ __launch_bounds__(256) void final_kernel(const float* __restrict__ H,
                                                    const float* __restrict__ acc3,
                                                    float* __restrict__ out) {
  __shared__ float tile[64 * 132];
  int b = blockIdx.y, n0 = blockIdx.x * 64;
  int t = threadIdx.x;
  int r = t >> 5;           // 0..7
  int c4 = (t & 31) * 4;    // 0..124
#pragma unroll
  for (int i = 0; i < 8; ++i) {
    int row = r + i * 8;
    *(float4*)&tile[row * 132 + c4] = *(const float4*)&H[(size_t)(b * N_ + n0 + row) * 128 + c4];
  }
  __syncthreads();
  int o = t >> 1;
  int nh = (t & 1) * 32;
  float s1 = acc3[(b * 128 + o) * 2], s2 = acc3[(b * 128 + o) * 2 + 1];
  const float inv = 1.f / (float)N_;
  float mean = s1 * inv;
  float var = fmaf(s2, inv, -mean * mean);
  float rs = rsqrtf(var + EPS_);
#pragma unroll
  for (int i = 0; i < 32; ++i) {
    int nl = nh + i;
    float v = tile[nl * 132 + o];
    float y = (v - mean) * rs;
    y = y > 0.f ? y : SLOPE_ * y;
    out[(size_t)(b * 128 + o) * N_ + n0 + nl] = y;   // f32 output (reference dtype)
  }
}

extern "C" void kernel_launch(void* const* d_in, const int* in_sizes, int n_in,
                              void* d_out, int out_size, void* d_ws, size_t ws_size,
                              hipStream_t stream) {
  const float* coords = (const float*)d_in[0];
  const float* feats = (const float*)d_in[1];
  const float* W1 = (const float*)d_in[2];
  const float* W2 = (const float*)d_in[3];
  const float* W3 = (const float*)d_in[4];
  char* ws = (char*)d_ws;
  int* idx = (int*)(ws + OFF_IDX);
  float4* cpk = (float4*)(ws + OFF_CPK);
  double4* cpk64 = (double4*)(ws + OFF_CPK64);
  float* acc = (float*)(ws + OFF_ACC);  // acc1 @ +0, acc2 @ +512, acc3 @ +1536 (floats)
  float* wc1 = (float*)(ws + OFF_WC1);
  float* wc2 = (float*)(ws + OFF_WC2);
  float* x3t = (float*)(ws + OFF_X3T);
  float* pq = (float*)(ws + OFF_PQ);   // pq1 (16MB) -> pq2 (32MB) -> ht (8MB), sequentially dead

  prep_kernel<<<456, 256, 0, stream>>>(coords, W1, W2, wc1, wc2, cpk, cpk64, acc);
  transpose_kernel<<<dim3(128, 2, 2), 256, 0, stream>>>(feats, x3t);
  knn_kernel<<<4096, 256, 0, stream>>>(cpk, cpk64, idx);
  // block 1: pq[b][n][0:128]=P1, [128:256]=Q1
  gemm_kernel<<<dim3(128, 4, 2), 256, 0, stream>>>(x3t, 512, wc1, 128, pq, 256, 128);
  edge_kernel<128><<<dim3(128, 2), 256, 0, stream>>>(pq, idx, x3t + 128, acc + 0);
  norm_kernel<128><<<(B_ * N_ * 128) / 256, 256, 0, stream>>>(x3t + 128, acc + 0);
  // block 2: pq[b][n][0:256]=P2, [256:512]=Q2
  gemm_kernel<<<dim3(128, 8, 2), 256, 0, stream>>>(x3t + 128, 512, wc2, 128, pq, 512, 128);
  edge_kernel<256><<<dim3(128, 2), 256, 0, stream>>>(pq, idx, x3t + 256, acc + 512);
  norm_kernel<256><<<(B_ * N_ * 256) / 256, 256, 0, stream>>>(x3t + 256, acc + 512);
  // final projection + inorm; ht aliases pq (pq2 dead)
  gemm_kernel<<<dim3(128, 2, 2), 256, 0, stream>>>(x3t, 512, W3, 512, pq, 128, 512);
  colred_kernel<<<dim3(32, 2), 256, 0, stream>>>(pq, acc + 1536);
  final_kernel<<<dim3(128, 2), 256, 0, stream>>>(pq, acc + 1536, (float*)d_out);
}